// Round 5
// baseline (102.201 us; speedup 1.0000x reference)
//
#include <hip/hip_runtime.h>
#include <math.h>

#define NROWS 262144
#define DDIM 64
#define NPROT 512
#define NBLK 512   // 512 rows per block in 2 chunks of 256; grid fully co-resident

typedef __attribute__((ext_vector_type(8))) short short8;
typedef __attribute__((ext_vector_type(4))) float f32x4;

__device__ __forceinline__ unsigned short f2bf(float f) {
    union { float f; unsigned u; } c; c.f = f;
    unsigned r = c.u + 0x7FFFu + ((c.u >> 16) & 1u);  // RNE
    return (unsigned short)(r >> 16);
}

__device__ __forceinline__ unsigned cvt_pk_bf16(float lo, float hi) {
    unsigned r;
    asm("v_cvt_pk_bf16_f32 %0, %1, %2" : "=v"(r) : "v"(lo), "v"(hi));
    return r;
}

// v = min(v, dpp-permuted v); CTRL compile-time (0xB1 xor1, 0x4E xor2,
// 0x141 row_half_mirror = xor4, 0x140 row_mirror = xor8) — within 16-lane rows
template <int CTRL>
__device__ __forceinline__ float dpp_min(float v) {
    int s = __builtin_amdgcn_update_dpp(__float_as_int(v), __float_as_int(v),
                                        CTRL, 0xF, 0xF, true);
    return fminf(v, __int_as_float(s));
}

// ---- pre-kernel: protos -> bf16(-2p); slot = jj*64 + t*16 + col ----
// p = (jj + 8t)*16 + col, class = jj*16 + col (t-free).
__global__ __launch_bounds__(64) void glvq_prep(
    const float* __restrict__ protos,
    float* __restrict__ psq_ws,
    uint4* __restrict__ pb_ws)
{
    const int p = blockIdx.x * 64 + threadIdx.x;  // 8 blocks x 64
    const int jj = (p >> 4) & 7, col = p & 15, t = p >> 7;
    const int slot = jj * 64 + t * 16 + col;
    const float* pr = protos + p * DDIM;
    float sq = 0.f;
#pragma unroll
    for (int c = 0; c < 8; ++c) {
        float4 v0 = *reinterpret_cast<const float4*>(pr + c * 8);
        float4 v1 = *reinterpret_cast<const float4*>(pr + c * 8 + 4);
        sq += v0.x * v0.x + v0.y * v0.y + v0.z * v0.z + v0.w * v0.w +
              v1.x * v1.x + v1.y * v1.y + v1.z * v1.z + v1.w * v1.w;
        union { unsigned short s[8]; uint4 u; } pk;
        pk.s[0] = f2bf(-2.f * v0.x); pk.s[1] = f2bf(-2.f * v0.y);
        pk.s[2] = f2bf(-2.f * v0.z); pk.s[3] = f2bf(-2.f * v0.w);
        pk.s[4] = f2bf(-2.f * v1.x); pk.s[5] = f2bf(-2.f * v1.y);
        pk.s[6] = f2bf(-2.f * v1.z); pk.s[7] = f2bf(-2.f * v1.w);
        pb_ws[(slot * 8 + c) ^ (slot & 7)] = pk.u;
    }
    // psq layout: [jj (8)][col (16)][t (4)]
    psq_ws[jj * 64 + col * 4 + t] = sq;
}

// 16 float4 loads covering 64 rows' worth for this wave (rows w*64+rt*16+col)
__device__ __forceinline__ void load_x16(const float* xb, float4 (&raw)[16], int g) {
#pragma unroll
    for (int rt = 0; rt < 4; ++rt)
#pragma unroll
        for (int kk = 0; kk < 2; ++kk) {
            raw[rt * 4 + kk * 2 + 0] =
                *reinterpret_cast<const float4*>(xb + rt * 1024 + kk * 32 + g * 8);
            raw[rt * 4 + kk * 2 + 1] =
                *reinterpret_cast<const float4*>(xb + rt * 1024 + kk * 32 + g * 8 + 4);
        }
}

// f32 -> bf16 A fragments + row norms into s_xsq slice (wave-local)
__device__ __forceinline__ void convert_chunk(const float4 (&raw)[16],
                                              short8 (&afrag)[4][2],
                                              float* xsq_slot, int g, int col) {
#pragma unroll
    for (int rt = 0; rt < 4; ++rt) {
        float part = 0.f;
#pragma unroll
        for (int kk = 0; kk < 2; ++kk) {
            float4 a0 = raw[rt * 4 + kk * 2 + 0];
            float4 a1 = raw[rt * 4 + kk * 2 + 1];
            part += a0.x * a0.x + a0.y * a0.y + a0.z * a0.z + a0.w * a0.w +
                    a1.x * a1.x + a1.y * a1.y + a1.z * a1.z + a1.w * a1.w;
            union { unsigned u[4]; short8 s; } pk;
            pk.u[0] = cvt_pk_bf16(a0.x, a0.y);
            pk.u[1] = cvt_pk_bf16(a0.z, a0.w);
            pk.u[2] = cvt_pk_bf16(a1.x, a1.y);
            pk.u[3] = cvt_pk_bf16(a1.z, a1.w);
            afrag[rt][kk] = pk.s;
        }
        part += __shfl_xor(part, 16);
        part += __shfl_xor(part, 32);
        if (g == 0) xsq_slot[rt * 16 + col] = part;
    }
}

// the proven R0 inner loop + epilogue over one 256-row chunk; returns lane lsum
__device__ __forceinline__ float chunk_pass(const short8 (&afrag)[4][2],
                                            const int (&jcv)[4][4],
                                            const char* pb0, const char* pb1,
                                            const char* pqc, const float* xsq_row,
                                            int w, int g, int col) {
    float m1[4][4], m2[4][4];
#pragma unroll
    for (int rt = 0; rt < 4; ++rt)
#pragma unroll
        for (int r = 0; r < 4; ++r) { m1[rt][r] = INFINITY; m2[rt][r] = INFINITY; }

#pragma unroll
    for (int jj = 0; jj < 8; ++jj) {
        // de-convoy: each wave walks the proto tiles in a rotated order
        const int jjr = (jj + 2 * w) & 7;
        const int bj = jjr * 8192;
        const f32x4 psqv = *reinterpret_cast<const f32x4*>(pqc + jjr * 256);
        float vmin[4][4];
#pragma unroll
        for (int rt = 0; rt < 4; ++rt)
#pragma unroll
            for (int r = 0; r < 4; ++r) vmin[rt][r] = INFINITY;
#pragma unroll
        for (int t = 0; t < 4; ++t) {
            short8 b0 = *reinterpret_cast<const short8*>(pb0 + bj + t * 2048);
            short8 b1 = *reinterpret_cast<const short8*>(pb1 + bj + t * 2048);
            const float sd = psqv[t];
#pragma unroll
            for (int rt = 0; rt < 4; ++rt) {
                f32x4 a = {sd, sd, sd, sd};  // seed acc with ||p||^2
                a = __builtin_amdgcn_mfma_f32_16x16x32_bf16(afrag[rt][0], b0, a, 0, 0, 0);
                a = __builtin_amdgcn_mfma_f32_16x16x32_bf16(afrag[rt][1], b1, a, 0, 0, 0);
#pragma unroll
                for (int r = 0; r < 4; ++r)
                    vmin[rt][r] = fminf(vmin[rt][r], a[r]);
            }
        }
#pragma unroll
        for (int rt = 0; rt < 4; ++rt)
#pragma unroll
            for (int r = 0; r < 4; ++r) {
                float v = vmin[rt][r];
                bool corr = (jcv[rt][r] == jjr);
                m1[rt][r] = corr ? v : m1[rt][r];                  // hits exactly once
                m2[rt][r] = corr ? m2[rt][r] : fminf(m2[rt][r], v);
            }
    }

    float lsum = 0.f;
#pragma unroll
    for (int rt = 0; rt < 4; ++rt)
#pragma unroll
        for (int r = 0; r < 4; ++r) {
            float a1 = m1[rt][r], a2 = m2[rt][r];
            a1 = dpp_min<0xB1>(a1);  a2 = dpp_min<0xB1>(a2);   // xor 1
            a1 = dpp_min<0x4E>(a1);  a2 = dpp_min<0x4E>(a2);   // xor 2
            a1 = dpp_min<0x141>(a1); a2 = dpp_min<0x141>(a2);  // xor 4
            a1 = dpp_min<0x140>(a1); a2 = dpp_min<0x140>(a2);  // xor 8
            float xsq = xsq_row[rt * 16 + g * 4 + r];
            float d1 = xsq + a1, d2 = xsq + a2;
            float mu = (d1 - d2) / (d1 + d2 + 1e-9f);
            float sig = 1.f / (1.f + __expf(-mu));
            lsum += (col == 0) ? sig : 0.f;
        }
    return lsum;
}

// ---- main kernel: 4 waves, 512 rows in 2 chunks; chunk-2 x-loads issued
// right after the barrier so they fly under chunk-1's compute pass ----
__global__ __launch_bounds__(256, 2) void glvq_main(
    const float* __restrict__ x,
    const int* __restrict__ y,
    const float* __restrict__ psq_ws,
    const uint4* __restrict__ pb_ws,
    float* __restrict__ partial)
{
    __shared__ uint4 s_pb[NPROT * 8];   // 64 KB: all bf16(-2p) protos, swizzled
    __shared__ float s_psq[NPROT];      // 2 KB, [jj][col][t]
    __shared__ float s_xsq[2][4][64];   // 2 KB (per chunk)
    __shared__ int   s_y[512];          // 2 KB
    __shared__ float s_red[4];

    const int tid = threadIdx.x;
    const int lane = tid & 63, w = tid >> 6;
    const int g = lane >> 4, col = lane & 15;
    const int row0 = blockIdx.x * 512;

    const float* xb = x + (size_t)(row0 + w * 64 + col) * DDIM;

    // chunk-1 x loads first (latency-critical)
    float4 raw[16];
    load_x16(xb, raw, g);

    // stage all protos + psq + y (ws is L2-resident)
#pragma unroll
    for (int i = 0; i < 16; ++i) s_pb[tid + 256 * i] = pb_ws[tid + 256 * i];
    s_psq[tid] = psq_ws[tid];
    s_psq[tid + 256] = psq_ws[tid + 256];
    s_y[tid] = y[row0 + tid];
    s_y[tid + 256] = y[row0 + 256 + tid];

    short8 afrag[4][2];
    convert_chunk(raw, afrag, &s_xsq[0][w][0], g, col);

    __syncthreads();  // protos/psq/y visible; only barrier before the end

    // corr <=> jcv[rt][r] == jj (chunk 1)
    int jcv[4][4];
#pragma unroll
    for (int rt = 0; rt < 4; ++rt)
#pragma unroll
        for (int r = 0; r < 4; ++r) {
            int yv = s_y[w * 64 + rt * 16 + g * 4 + r];
            jcv[rt][r] = ((yv & 15) == col) ? (yv >> 4) : 15;
        }

    // issue chunk-2 x loads AFTER the barrier (barrier would drain vmcnt):
    // their HBM latency hides under the ~12 us chunk-1 pass below
    float4 raw2[16];
    load_x16(xb + 256 * DDIM, raw2, g);

    // per-lane constant LDS bases; t offsets fold into ds immediates
    const int sw = (col & 7) << 4;
    const char* s_pb_c = (const char*)s_pb;
    const char* pb0 = s_pb_c + col * 128 + ((g * 16) ^ sw);
    const char* pb1 = s_pb_c + col * 128 + ((g * 16 + 64) ^ sw);
    const char* pqc = (const char*)s_psq + col * 16;

    float lsum = chunk_pass(afrag, jcv, pb0, pb1, pqc, &s_xsq[0][w][0], w, g, col);

    // chunk 2: jcv, convert (vmcnt wait lands here — raw2 already arrived), pass
#pragma unroll
    for (int rt = 0; rt < 4; ++rt)
#pragma unroll
        for (int r = 0; r < 4; ++r) {
            int yv = s_y[256 + w * 64 + rt * 16 + g * 4 + r];
            jcv[rt][r] = ((yv & 15) == col) ? (yv >> 4) : 15;
        }
    short8 afrag2[4][2];
    convert_chunk(raw2, afrag2, &s_xsq[1][w][0], g, col);
    lsum += chunk_pass(afrag2, jcv, pb0, pb1, pqc, &s_xsq[1][w][0], w, g, col);

    // block reduction -> partial (plain store; finalize kernel reads it)
#pragma unroll
    for (int mk = 1; mk <= 32; mk <<= 1) lsum += __shfl_xor(lsum, mk);
    if (lane == 0) s_red[w] = lsum;
    __syncthreads();
    if (tid == 0)
        partial[blockIdx.x] = (s_red[0] + s_red[1]) + (s_red[2] + s_red[3]);
}

__global__ __launch_bounds__(256) void glvq_finalize(
    const float* __restrict__ partial, int nparts, float* __restrict__ out)
{
    __shared__ float s_red[256];
    const int tid = threadIdx.x;
    float acc = 0.f;
    for (int i = tid; i < nparts; i += 256) acc += partial[i];
    s_red[tid] = acc;
    __syncthreads();
#pragma unroll
    for (int s = 128; s >= 1; s >>= 1) {
        if (tid < s) s_red[tid] += s_red[tid + s];
        __syncthreads();
    }
    if (tid == 0) out[0] = s_red[0] * (1.0f / (float)NROWS);
}

extern "C" void kernel_launch(void* const* d_in, const int* in_sizes, int n_in,
                              void* d_out, int out_size, void* d_ws, size_t ws_size,
                              hipStream_t stream) {
    const float* x = (const float*)d_in[0];
    const float* protos = (const float*)d_in[1];
    const int* y = (const int*)d_in[2];
    float* out = (float*)d_out;

    // ws layout: [0..4K) partials (512 used) | [4K..6K) psq | [6K..70K) bf16 protos
    float* partial = (float*)d_ws;
    float* psq_ws = (float*)((char*)d_ws + 4096);
    uint4* pb_ws = (uint4*)((char*)d_ws + 6144);

    glvq_prep<<<8, 64, 0, stream>>>(protos, psq_ws, pb_ws);
    glvq_main<<<NBLK, 256, 0, stream>>>(x, y, psq_ws, pb_ws, partial);
    glvq_finalize<<<1, 256, 0, stream>>>(partial, NBLK, out);
}

// Round 6
// 53.565 us; speedup vs baseline: 1.9080x; 1.9080x over previous
//
#include <hip/hip_runtime.h>
#include <math.h>

#define NROWS 262144
#define DDIM 64
#define NPROT 512
#define NBLK 512   // 512 rows per block in 2 chunks of 256; grid fully co-resident

typedef __attribute__((ext_vector_type(8))) short short8;
typedef __attribute__((ext_vector_type(4))) float f32x4;

__device__ __forceinline__ unsigned short f2bf(float f) {
    union { float f; unsigned u; } c; c.f = f;
    unsigned r = c.u + 0x7FFFu + ((c.u >> 16) & 1u);  // RNE
    return (unsigned short)(r >> 16);
}

__device__ __forceinline__ unsigned cvt_pk_bf16(float lo, float hi) {
    unsigned r;
    asm("v_cvt_pk_bf16_f32 %0, %1, %2" : "=v"(r) : "v"(lo), "v"(hi));
    return r;
}

// v = min(v, dpp-permuted v); CTRL compile-time (0xB1 xor1, 0x4E xor2,
// 0x141 row_half_mirror = xor4, 0x140 row_mirror = xor8) — within 16-lane rows
template <int CTRL>
__device__ __forceinline__ float dpp_min(float v) {
    int s = __builtin_amdgcn_update_dpp(__float_as_int(v), __float_as_int(v),
                                        CTRL, 0xF, 0xF, true);
    return fminf(v, __int_as_float(s));
}

// ---- pre-kernel: protos -> bf16(-2p); slot = jj*64 + t*16 + col ----
// p = (jj + 8t)*16 + col, class = jj*16 + col (t-free).
__global__ __launch_bounds__(64) void glvq_prep(
    const float* __restrict__ protos,
    float* __restrict__ psq_ws,
    uint4* __restrict__ pb_ws)
{
    const int p = blockIdx.x * 64 + threadIdx.x;  // 8 blocks x 64
    const int jj = (p >> 4) & 7, col = p & 15, t = p >> 7;
    const int slot = jj * 64 + t * 16 + col;
    const float* pr = protos + p * DDIM;
    float sq = 0.f;
#pragma unroll
    for (int c = 0; c < 8; ++c) {
        float4 v0 = *reinterpret_cast<const float4*>(pr + c * 8);
        float4 v1 = *reinterpret_cast<const float4*>(pr + c * 8 + 4);
        sq += v0.x * v0.x + v0.y * v0.y + v0.z * v0.z + v0.w * v0.w +
              v1.x * v1.x + v1.y * v1.y + v1.z * v1.z + v1.w * v1.w;
        union { unsigned short s[8]; uint4 u; } pk;
        pk.s[0] = f2bf(-2.f * v0.x); pk.s[1] = f2bf(-2.f * v0.y);
        pk.s[2] = f2bf(-2.f * v0.z); pk.s[3] = f2bf(-2.f * v0.w);
        pk.s[4] = f2bf(-2.f * v1.x); pk.s[5] = f2bf(-2.f * v1.y);
        pk.s[6] = f2bf(-2.f * v1.z); pk.s[7] = f2bf(-2.f * v1.w);
        pb_ws[(slot * 8 + c) ^ (slot & 7)] = pk.u;
    }
    // psq layout: [jj (8)][col (16)][t (4)]
    psq_ws[jj * 64 + col * 4 + t] = sq;
}

// 16 float4 loads covering 64 rows' worth for this wave (rows w*64+rt*16+col)
__device__ __forceinline__ void load_x16(const float* xb, float4 (&raw)[16], int g) {
#pragma unroll
    for (int rt = 0; rt < 4; ++rt)
#pragma unroll
        for (int kk = 0; kk < 2; ++kk) {
            raw[rt * 4 + kk * 2 + 0] =
                *reinterpret_cast<const float4*>(xb + rt * 1024 + kk * 32 + g * 8);
            raw[rt * 4 + kk * 2 + 1] =
                *reinterpret_cast<const float4*>(xb + rt * 1024 + kk * 32 + g * 8 + 4);
        }
}

// f32 -> bf16 A fragments + row norms into s_xsq slice (wave-local)
__device__ __forceinline__ void convert_chunk(const float4 (&raw)[16],
                                              short8 (&afrag)[4][2],
                                              float* xsq_slot, int g, int col) {
#pragma unroll
    for (int rt = 0; rt < 4; ++rt) {
        float part = 0.f;
#pragma unroll
        for (int kk = 0; kk < 2; ++kk) {
            float4 a0 = raw[rt * 4 + kk * 2 + 0];
            float4 a1 = raw[rt * 4 + kk * 2 + 1];
            part += a0.x * a0.x + a0.y * a0.y + a0.z * a0.z + a0.w * a0.w +
                    a1.x * a1.x + a1.y * a1.y + a1.z * a1.z + a1.w * a1.w;
            union { unsigned u[4]; short8 s; } pk;
            pk.u[0] = cvt_pk_bf16(a0.x, a0.y);
            pk.u[1] = cvt_pk_bf16(a0.z, a0.w);
            pk.u[2] = cvt_pk_bf16(a1.x, a1.y);
            pk.u[3] = cvt_pk_bf16(a1.z, a1.w);
            afrag[rt][kk] = pk.s;
        }
        part += __shfl_xor(part, 16);
        part += __shfl_xor(part, 32);
        if (g == 0) xsq_slot[rt * 16 + col] = part;
    }
}

// the proven R0 inner loop + epilogue over one 256-row chunk; returns lane lsum
__device__ __forceinline__ float chunk_pass(const short8 (&afrag)[4][2],
                                            const int (&jcv)[4][4],
                                            const char* pb0, const char* pb1,
                                            const char* pqc, const float* xsq_row,
                                            int w, int g, int col) {
    float m1[4][4], m2[4][4];
#pragma unroll
    for (int rt = 0; rt < 4; ++rt)
#pragma unroll
        for (int r = 0; r < 4; ++r) { m1[rt][r] = INFINITY; m2[rt][r] = INFINITY; }

#pragma unroll
    for (int jj = 0; jj < 8; ++jj) {
        // de-convoy: each wave walks the proto tiles in a rotated order
        const int jjr = (jj + 2 * w) & 7;
        const int bj = jjr * 8192;
        const f32x4 psqv = *reinterpret_cast<const f32x4*>(pqc + jjr * 256);
        float vmin[4][4];
#pragma unroll
        for (int rt = 0; rt < 4; ++rt)
#pragma unroll
            for (int r = 0; r < 4; ++r) vmin[rt][r] = INFINITY;
#pragma unroll
        for (int t = 0; t < 4; ++t) {
            short8 b0 = *reinterpret_cast<const short8*>(pb0 + bj + t * 2048);
            short8 b1 = *reinterpret_cast<const short8*>(pb1 + bj + t * 2048);
            const float sd = psqv[t];
#pragma unroll
            for (int rt = 0; rt < 4; ++rt) {
                f32x4 a = {sd, sd, sd, sd};  // seed acc with ||p||^2
                a = __builtin_amdgcn_mfma_f32_16x16x32_bf16(afrag[rt][0], b0, a, 0, 0, 0);
                a = __builtin_amdgcn_mfma_f32_16x16x32_bf16(afrag[rt][1], b1, a, 0, 0, 0);
#pragma unroll
                for (int r = 0; r < 4; ++r)
                    vmin[rt][r] = fminf(vmin[rt][r], a[r]);
            }
        }
#pragma unroll
        for (int rt = 0; rt < 4; ++rt)
#pragma unroll
            for (int r = 0; r < 4; ++r) {
                float v = vmin[rt][r];
                bool corr = (jcv[rt][r] == jjr);
                m1[rt][r] = corr ? v : m1[rt][r];                  // hits exactly once
                m2[rt][r] = corr ? m2[rt][r] : fminf(m2[rt][r], v);
            }
    }

    float lsum = 0.f;
#pragma unroll
    for (int rt = 0; rt < 4; ++rt)
#pragma unroll
        for (int r = 0; r < 4; ++r) {
            float a1 = m1[rt][r], a2 = m2[rt][r];
            a1 = dpp_min<0xB1>(a1);  a2 = dpp_min<0xB1>(a2);   // xor 1
            a1 = dpp_min<0x4E>(a1);  a2 = dpp_min<0x4E>(a2);   // xor 2
            a1 = dpp_min<0x141>(a1); a2 = dpp_min<0x141>(a2);  // xor 4
            a1 = dpp_min<0x140>(a1); a2 = dpp_min<0x140>(a2);  // xor 8
            float xsq = xsq_row[rt * 16 + g * 4 + r];
            float d1 = xsq + a1, d2 = xsq + a2;
            float mu = (d1 - d2) / (d1 + d2 + 1e-9f);
            float sig = 1.f / (1.f + __expf(-mu));
            lsum += (col == 0) ? sig : 0.f;
        }
    return lsum;
}

// ---- main kernel: 4 waves, 512 rows in 2 chunks; chunk-2 x-loads issued
// right after the barrier so they fly under chunk-1's compute pass.
// __launch_bounds__(256, 1): this toolchain's VGPR cap = 256/min_waves_arg
// (evidence: (512,4)->64, (256,2)->128, (512,2)->128). Need ~164 live regs
// for the held prefetch -> min_waves=1 gives the 256 cap. Occupancy is
// LDS-limited to 2 blocks/CU regardless, so this costs nothing.
__global__ __launch_bounds__(256, 1) void glvq_main(
    const float* __restrict__ x,
    const int* __restrict__ y,
    const float* __restrict__ psq_ws,
    const uint4* __restrict__ pb_ws,
    float* __restrict__ partial)
{
    __shared__ uint4 s_pb[NPROT * 8];   // 64 KB: all bf16(-2p) protos, swizzled
    __shared__ float s_psq[NPROT];      // 2 KB, [jj][col][t]
    __shared__ float s_xsq[2][4][64];   // 2 KB (per chunk)
    __shared__ int   s_y[512];          // 2 KB
    __shared__ float s_red[4];

    const int tid = threadIdx.x;
    const int lane = tid & 63, w = tid >> 6;
    const int g = lane >> 4, col = lane & 15;
    const int row0 = blockIdx.x * 512;

    const float* xb = x + (size_t)(row0 + w * 64 + col) * DDIM;

    // chunk-1 x loads first (latency-critical)
    float4 raw[16];
    load_x16(xb, raw, g);

    // stage all protos + psq + y (ws is L2-resident)
#pragma unroll
    for (int i = 0; i < 16; ++i) s_pb[tid + 256 * i] = pb_ws[tid + 256 * i];
    s_psq[tid] = psq_ws[tid];
    s_psq[tid + 256] = psq_ws[tid + 256];
    s_y[tid] = y[row0 + tid];
    s_y[tid + 256] = y[row0 + 256 + tid];

    short8 afrag[4][2];
    convert_chunk(raw, afrag, &s_xsq[0][w][0], g, col);

    __syncthreads();  // protos/psq/y visible; only barrier before the end

    // corr <=> jcv[rt][r] == jj (chunk 1)
    int jcv[4][4];
#pragma unroll
    for (int rt = 0; rt < 4; ++rt)
#pragma unroll
        for (int r = 0; r < 4; ++r) {
            int yv = s_y[w * 64 + rt * 16 + g * 4 + r];
            jcv[rt][r] = ((yv & 15) == col) ? (yv >> 4) : 15;
        }

    // issue chunk-2 x loads AFTER the barrier (barrier would drain vmcnt):
    // their HBM latency hides under the ~12 us chunk-1 pass below
    float4 raw2[16];
    load_x16(xb + 256 * DDIM, raw2, g);

    // per-lane constant LDS bases; t offsets fold into ds immediates
    const int sw = (col & 7) << 4;
    const char* s_pb_c = (const char*)s_pb;
    const char* pb0 = s_pb_c + col * 128 + ((g * 16) ^ sw);
    const char* pb1 = s_pb_c + col * 128 + ((g * 16 + 64) ^ sw);
    const char* pqc = (const char*)s_psq + col * 16;

    float lsum = chunk_pass(afrag, jcv, pb0, pb1, pqc, &s_xsq[0][w][0], w, g, col);

    // chunk 2: jcv, convert (vmcnt wait lands here — raw2 already arrived), pass
#pragma unroll
    for (int rt = 0; rt < 4; ++rt)
#pragma unroll
        for (int r = 0; r < 4; ++r) {
            int yv = s_y[256 + w * 64 + rt * 16 + g * 4 + r];
            jcv[rt][r] = ((yv & 15) == col) ? (yv >> 4) : 15;
        }
    short8 afrag2[4][2];
    convert_chunk(raw2, afrag2, &s_xsq[1][w][0], g, col);
    lsum += chunk_pass(afrag2, jcv, pb0, pb1, pqc, &s_xsq[1][w][0], w, g, col);

    // block reduction -> partial (plain store; finalize kernel reads it)
#pragma unroll
    for (int mk = 1; mk <= 32; mk <<= 1) lsum += __shfl_xor(lsum, mk);
    if (lane == 0) s_red[w] = lsum;
    __syncthreads();
    if (tid == 0)
        partial[blockIdx.x] = (s_red[0] + s_red[1]) + (s_red[2] + s_red[3]);
}

__global__ __launch_bounds__(256) void glvq_finalize(
    const float* __restrict__ partial, int nparts, float* __restrict__ out)
{
    __shared__ float s_red[256];
    const int tid = threadIdx.x;
    float acc = 0.f;
    for (int i = tid; i < nparts; i += 256) acc += partial[i];
    s_red[tid] = acc;
    __syncthreads();
#pragma unroll
    for (int s = 128; s >= 1; s >>= 1) {
        if (tid < s) s_red[tid] += s_red[tid + s];
        __syncthreads();
    }
    if (tid == 0) out[0] = s_red[0] * (1.0f / (float)NROWS);
}

extern "C" void kernel_launch(void* const* d_in, const int* in_sizes, int n_in,
                              void* d_out, int out_size, void* d_ws, size_t ws_size,
                              hipStream_t stream) {
    const float* x = (const float*)d_in[0];
    const float* protos = (const float*)d_in[1];
    const int* y = (const int*)d_in[2];
    float* out = (float*)d_out;

    // ws layout: [0..4K) partials (512 used) | [4K..6K) psq | [6K..70K) bf16 protos
    float* partial = (float*)d_ws;
    float* psq_ws = (float*)((char*)d_ws + 4096);
    uint4* pb_ws = (uint4*)((char*)d_ws + 6144);

    glvq_prep<<<8, 64, 0, stream>>>(protos, psq_ws, pb_ws);
    glvq_main<<<NBLK, 256, 0, stream>>>(x, y, psq_ws, pb_ws, partial);
    glvq_finalize<<<1, 256, 0, stream>>>(partial, NBLK, out);
}

// Round 7
// 43.184 us; speedup vs baseline: 2.3667x; 1.2404x over previous
//
#include <hip/hip_runtime.h>
#include <math.h>

#define NROWS 262144
#define DDIM 64
#define NPROT 512
#define NBLK 2048  // 128 rows per block: deeper launch pipeline (4 generations)
#define RT 2       // row-tiles per wave (32 rows/wave)

typedef __attribute__((ext_vector_type(8))) short short8;
typedef __attribute__((ext_vector_type(4))) float f32x4;

__device__ __forceinline__ unsigned short f2bf(float f) {
    union { float f; unsigned u; } c; c.f = f;
    unsigned r = c.u + 0x7FFFu + ((c.u >> 16) & 1u);  // RNE
    return (unsigned short)(r >> 16);
}

__device__ __forceinline__ unsigned cvt_pk_bf16(float lo, float hi) {
    unsigned r;
    asm("v_cvt_pk_bf16_f32 %0, %1, %2" : "=v"(r) : "v"(lo), "v"(hi));
    return r;
}

// v = min(v, dpp-permuted v); CTRL compile-time (0xB1 xor1, 0x4E xor2,
// 0x141 row_half_mirror = xor4, 0x140 row_mirror = xor8) — within 16-lane rows
template <int CTRL>
__device__ __forceinline__ float dpp_min(float v) {
    int s = __builtin_amdgcn_update_dpp(__float_as_int(v), __float_as_int(v),
                                        CTRL, 0xF, 0xF, true);
    return fminf(v, __int_as_float(s));
}

// ---- pre-kernel: protos -> bf16(-2p); slot = jj*64 + t*16 + col ----
// p = (jj + 8t)*16 + col, class = jj*16 + col (t-free).
__global__ __launch_bounds__(64) void glvq_prep(
    const float* __restrict__ protos,
    float* __restrict__ psq_ws,
    uint4* __restrict__ pb_ws)
{
    const int p = blockIdx.x * 64 + threadIdx.x;  // 8 blocks x 64
    const int jj = (p >> 4) & 7, col = p & 15, t = p >> 7;
    const int slot = jj * 64 + t * 16 + col;
    const float* pr = protos + p * DDIM;
    float sq = 0.f;
#pragma unroll
    for (int c = 0; c < 8; ++c) {
        float4 v0 = *reinterpret_cast<const float4*>(pr + c * 8);
        float4 v1 = *reinterpret_cast<const float4*>(pr + c * 8 + 4);
        sq += v0.x * v0.x + v0.y * v0.y + v0.z * v0.z + v0.w * v0.w +
              v1.x * v1.x + v1.y * v1.y + v1.z * v1.z + v1.w * v1.w;
        union { unsigned short s[8]; uint4 u; } pk;
        pk.s[0] = f2bf(-2.f * v0.x); pk.s[1] = f2bf(-2.f * v0.y);
        pk.s[2] = f2bf(-2.f * v0.z); pk.s[3] = f2bf(-2.f * v0.w);
        pk.s[4] = f2bf(-2.f * v1.x); pk.s[5] = f2bf(-2.f * v1.y);
        pk.s[6] = f2bf(-2.f * v1.z); pk.s[7] = f2bf(-2.f * v1.w);
        pb_ws[(slot * 8 + c) ^ (slot & 7)] = pk.u;
    }
    // psq layout: [jj (8)][col (16)][t (4)]
    psq_ws[jj * 64 + col * 4 + t] = sq;
}

// ---- main kernel: 4 waves x 32 rows (128 rows/block), R0 inner loop ----
__global__ __launch_bounds__(256, 2) void glvq_main(
    const float* __restrict__ x,
    const int* __restrict__ y,
    const float* __restrict__ psq_ws,
    const uint4* __restrict__ pb_ws,
    float* __restrict__ partial)
{
    __shared__ uint4 s_pb[NPROT * 8];   // 64 KB: all bf16(-2p) protos, swizzled
    __shared__ float s_psq[NPROT];      // 2 KB, [jj][col][t]
    __shared__ float s_xsq[4][32];      // 0.5 KB
    __shared__ int   s_y[128];          // 0.5 KB
    __shared__ float s_red[4];

    const int tid = threadIdx.x;
    const int lane = tid & 63, w = tid >> 6;
    const int g = lane >> 4, col = lane & 15;
    const int row0 = blockIdx.x * 128;

    // x loads first (latency-critical): row = row0 + w*32 + rt*16 + col
    float4 raw[RT * 4];
    {
        const float* xb = x + (size_t)(row0 + w * 32 + col) * DDIM;
#pragma unroll
        for (int rt = 0; rt < RT; ++rt)
#pragma unroll
            for (int kk = 0; kk < 2; ++kk) {
                raw[rt * 4 + kk * 2 + 0] =
                    *reinterpret_cast<const float4*>(xb + rt * 1024 + kk * 32 + g * 8);
                raw[rt * 4 + kk * 2 + 1] =
                    *reinterpret_cast<const float4*>(xb + rt * 1024 + kk * 32 + g * 8 + 4);
            }
    }

    // stage all protos + psq + y (ws is L2-resident)
#pragma unroll
    for (int i = 0; i < 16; ++i) s_pb[tid + 256 * i] = pb_ws[tid + 256 * i];
    s_psq[tid] = psq_ws[tid];
    s_psq[tid + 256] = psq_ws[tid + 256];
    if (tid < 128) s_y[tid] = y[row0 + tid];

    // convert to A fragments + row norms
    short8 afrag[RT][2];
#pragma unroll
    for (int rt = 0; rt < RT; ++rt) {
        float part = 0.f;
#pragma unroll
        for (int kk = 0; kk < 2; ++kk) {
            float4 a0 = raw[rt * 4 + kk * 2 + 0];
            float4 a1 = raw[rt * 4 + kk * 2 + 1];
            part += a0.x * a0.x + a0.y * a0.y + a0.z * a0.z + a0.w * a0.w +
                    a1.x * a1.x + a1.y * a1.y + a1.z * a1.z + a1.w * a1.w;
            union { unsigned u[4]; short8 s; } pk;
            pk.u[0] = cvt_pk_bf16(a0.x, a0.y);
            pk.u[1] = cvt_pk_bf16(a0.z, a0.w);
            pk.u[2] = cvt_pk_bf16(a1.x, a1.y);
            pk.u[3] = cvt_pk_bf16(a1.z, a1.w);
            afrag[rt][kk] = pk.s;
        }
        part += __shfl_xor(part, 16);
        part += __shfl_xor(part, 32);
        if (g == 0) s_xsq[w][rt * 16 + col] = part;
    }

    __syncthreads();  // protos/psq/y visible; only barrier before the end

    // corr <=> jcv[rt][r] == jj
    int jcv[RT][4];
#pragma unroll
    for (int rt = 0; rt < RT; ++rt)
#pragma unroll
        for (int r = 0; r < 4; ++r) {
            int yv = s_y[w * 32 + rt * 16 + g * 4 + r];
            jcv[rt][r] = ((yv & 15) == col) ? (yv >> 4) : 15;
        }

    float m1[RT][4], m2[RT][4];
#pragma unroll
    for (int rt = 0; rt < RT; ++rt)
#pragma unroll
        for (int r = 0; r < 4; ++r) { m1[rt][r] = INFINITY; m2[rt][r] = INFINITY; }

    // per-lane constant LDS bases; t offsets fold into ds immediates
    const int sw = (col & 7) << 4;
    const char* s_pb_c = (const char*)s_pb;
    const char* pb0 = s_pb_c + col * 128 + ((g * 16) ^ sw);
    const char* pb1 = s_pb_c + col * 128 + ((g * 16 + 64) ^ sw);
    const char* pqc = (const char*)s_psq + col * 16;

#pragma unroll
    for (int jj = 0; jj < 8; ++jj) {
        // de-convoy: each wave walks the proto tiles in a rotated order
        const int jjr = (jj + 2 * w) & 7;
        const int bj = jjr * 8192;
        const f32x4 psqv = *reinterpret_cast<const f32x4*>(pqc + jjr * 256);
        float vmin[RT][4];
#pragma unroll
        for (int rt = 0; rt < RT; ++rt)
#pragma unroll
            for (int r = 0; r < 4; ++r) vmin[rt][r] = INFINITY;
#pragma unroll
        for (int t = 0; t < 4; ++t) {
            short8 b0 = *reinterpret_cast<const short8*>(pb0 + bj + t * 2048);
            short8 b1 = *reinterpret_cast<const short8*>(pb1 + bj + t * 2048);
            const float sd = psqv[t];
#pragma unroll
            for (int rt = 0; rt < RT; ++rt) {
                f32x4 a = {sd, sd, sd, sd};  // seed acc with ||p||^2
                a = __builtin_amdgcn_mfma_f32_16x16x32_bf16(afrag[rt][0], b0, a, 0, 0, 0);
                a = __builtin_amdgcn_mfma_f32_16x16x32_bf16(afrag[rt][1], b1, a, 0, 0, 0);
#pragma unroll
                for (int r = 0; r < 4; ++r)
                    vmin[rt][r] = fminf(vmin[rt][r], a[r]);
            }
        }
#pragma unroll
        for (int rt = 0; rt < RT; ++rt)
#pragma unroll
            for (int r = 0; r < 4; ++r) {
                float v = vmin[rt][r];
                bool corr = (jcv[rt][r] == jjr);
                m1[rt][r] = corr ? v : m1[rt][r];                  // hits exactly once
                m2[rt][r] = corr ? m2[rt][r] : fminf(m2[rt][r], v);
            }
    }

    // epilogue: DPP min over 16 proto-columns (within 16-lane rows), mu/sigmoid
    float lsum = 0.f;
#pragma unroll
    for (int rt = 0; rt < RT; ++rt)
#pragma unroll
        for (int r = 0; r < 4; ++r) {
            float a1 = m1[rt][r], a2 = m2[rt][r];
            a1 = dpp_min<0xB1>(a1);  a2 = dpp_min<0xB1>(a2);   // xor 1
            a1 = dpp_min<0x4E>(a1);  a2 = dpp_min<0x4E>(a2);   // xor 2
            a1 = dpp_min<0x141>(a1); a2 = dpp_min<0x141>(a2);  // xor 4
            a1 = dpp_min<0x140>(a1); a2 = dpp_min<0x140>(a2);  // xor 8
            float xsq = s_xsq[w][rt * 16 + g * 4 + r];
            float d1 = xsq + a1, d2 = xsq + a2;
            float mu = (d1 - d2) / (d1 + d2 + 1e-9f);
            float sig = 1.f / (1.f + __expf(-mu));
            lsum += (col == 0) ? sig : 0.f;
        }
#pragma unroll
    for (int mk = 1; mk <= 32; mk <<= 1) lsum += __shfl_xor(lsum, mk);
    if (lane == 0) s_red[w] = lsum;
    __syncthreads();
    if (tid == 0)
        partial[blockIdx.x] = (s_red[0] + s_red[1]) + (s_red[2] + s_red[3]);
}

__global__ __launch_bounds__(256) void glvq_finalize(
    const float* __restrict__ partial, int nparts, float* __restrict__ out)
{
    __shared__ float s_red[256];
    const int tid = threadIdx.x;
    float acc = 0.f;
    for (int i = tid; i < nparts; i += 256) acc += partial[i];
    s_red[tid] = acc;
    __syncthreads();
#pragma unroll
    for (int s = 128; s >= 1; s >>= 1) {
        if (tid < s) s_red[tid] += s_red[tid + s];
        __syncthreads();
    }
    if (tid == 0) out[0] = s_red[0] * (1.0f / (float)NROWS);
}

extern "C" void kernel_launch(void* const* d_in, const int* in_sizes, int n_in,
                              void* d_out, int out_size, void* d_ws, size_t ws_size,
                              hipStream_t stream) {
    const float* x = (const float*)d_in[0];
    const float* protos = (const float*)d_in[1];
    const int* y = (const int*)d_in[2];
    float* out = (float*)d_out;

    // ws layout: [0..8K) partials (2048) | [8K..10K) psq | [10K..74K) bf16 protos
    float* partial = (float*)d_ws;
    float* psq_ws = (float*)((char*)d_ws + 8192);
    uint4* pb_ws = (uint4*)((char*)d_ws + 10240);

    glvq_prep<<<8, 64, 0, stream>>>(protos, psq_ws, pb_ws);
    glvq_main<<<NBLK, 256, 0, stream>>>(x, y, psq_ws, pb_ws, partial);
    glvq_finalize<<<1, 256, 0, stream>>>(partial, NBLK, out);
}

// Round 8
// 39.567 us; speedup vs baseline: 2.5830x; 1.0914x over previous
//
#include <hip/hip_runtime.h>
#include <math.h>

#define NROWS 262144
#define DDIM 64
#define NPROT 512
#define NBLK 1024  // main grid: 256 rows per block (proven R0 geometry)

typedef __attribute__((ext_vector_type(8))) short short8;
typedef __attribute__((ext_vector_type(4))) float f32x4;
typedef __attribute__((address_space(1))) const unsigned int gu32;
typedef __attribute__((address_space(3))) unsigned int lu32;

__device__ __forceinline__ unsigned short f2bf(float f) {
    union { float f; unsigned u; } c; c.f = f;
    unsigned r = c.u + 0x7FFFu + ((c.u >> 16) & 1u);  // RNE
    return (unsigned short)(r >> 16);
}

__device__ __forceinline__ unsigned cvt_pk_bf16(float lo, float hi) {
    unsigned r;
    asm("v_cvt_pk_bf16_f32 %0, %1, %2" : "=v"(r) : "v"(lo), "v"(hi));
    return r;
}

// v = min(v, dpp-permuted v); CTRL compile-time (0xB1 xor1, 0x4E xor2,
// 0x141 row_half_mirror = xor4, 0x140 row_mirror = xor8) — within 16-lane rows
template <int CTRL>
__device__ __forceinline__ float dpp_min(float v) {
    int s = __builtin_amdgcn_update_dpp(__float_as_int(v), __float_as_int(v),
                                        CTRL, 0xF, 0xF, true);
    return fminf(v, __int_as_float(s));
}

// ---- pre-kernel: protos -> bf16(-2p); slot = jj*64 + t*16 + col ----
// p = (jj + 8t)*16 + col, class = jj*16 + col (t-free).
__global__ __launch_bounds__(64) void glvq_prep(
    const float* __restrict__ protos,
    float* __restrict__ psq_ws,
    uint4* __restrict__ pb_ws)
{
    const int p = blockIdx.x * 64 + threadIdx.x;  // 8 blocks x 64
    const int jj = (p >> 4) & 7, col = p & 15, t = p >> 7;
    const int slot = jj * 64 + t * 16 + col;
    const float* pr = protos + p * DDIM;
    float sq = 0.f;
#pragma unroll
    for (int c = 0; c < 8; ++c) {
        float4 v0 = *reinterpret_cast<const float4*>(pr + c * 8);
        float4 v1 = *reinterpret_cast<const float4*>(pr + c * 8 + 4);
        sq += v0.x * v0.x + v0.y * v0.y + v0.z * v0.z + v0.w * v0.w +
              v1.x * v1.x + v1.y * v1.y + v1.z * v1.z + v1.w * v1.w;
        union { unsigned short s[8]; uint4 u; } pk;
        pk.s[0] = f2bf(-2.f * v0.x); pk.s[1] = f2bf(-2.f * v0.y);
        pk.s[2] = f2bf(-2.f * v0.z); pk.s[3] = f2bf(-2.f * v0.w);
        pk.s[4] = f2bf(-2.f * v1.x); pk.s[5] = f2bf(-2.f * v1.y);
        pk.s[6] = f2bf(-2.f * v1.z); pk.s[7] = f2bf(-2.f * v1.w);
        pb_ws[(slot * 8 + c) ^ (slot & 7)] = pk.u;
    }
    // psq layout: [jj (8)][col (16)][t (4)]
    psq_ws[jj * 64 + col * 4 + t] = sq;
}

// ---- main kernel: 4 waves x 64 rows, all protos resident, de-convoyed.
// Single change vs the 39.07us baseline: proto staging via async
// global_load_lds DMA (width 16) — no VGPR round-trip, no ds_writes;
// staging flies under the x-load/convert phase; __syncthreads drains vmcnt.
__global__ __launch_bounds__(256, 2) void glvq_main(
    const float* __restrict__ x,
    const int* __restrict__ y,
    const float* __restrict__ psq_ws,
    const uint4* __restrict__ pb_ws,
    float* __restrict__ partial)
{
    __shared__ uint4 s_pb[NPROT * 8];   // 64 KB: all bf16(-2p) protos, swizzled
    __shared__ float s_psq[NPROT];      // 2 KB, [jj][col][t]
    __shared__ float s_xsq[4][64];      // 1 KB
    __shared__ int   s_y[256];          // 1 KB
    __shared__ float s_red[4];

    const int tid = threadIdx.x;
    const int lane = tid & 63, w = tid >> 6;
    const int g = lane >> 4, col = lane & 15;
    const int row0 = blockIdx.x * 256;

    // x loads first (latency-critical): row = row0 + w*64 + rt*16 + col
    float4 raw[16];
    {
        const float* xb = x + (size_t)(row0 + w * 64 + col) * DDIM;
#pragma unroll
        for (int rt = 0; rt < 4; ++rt)
#pragma unroll
            for (int kk = 0; kk < 2; ++kk) {
                raw[rt * 4 + kk * 2 + 0] =
                    *reinterpret_cast<const float4*>(xb + rt * 1024 + kk * 32 + g * 8);
                raw[rt * 4 + kk * 2 + 1] =
                    *reinterpret_cast<const float4*>(xb + rt * 1024 + kk * 32 + g * 8 + 4);
            }
    }

    // stage all protos via global->LDS DMA: per wave, dst = uniform base +
    // lane*16 (linear layout; pb_ws is already pre-swizzled). 16 B/lane/op.
#pragma unroll
    for (int i = 0; i < 16; ++i)
        __builtin_amdgcn_global_load_lds(
            (gu32*)(pb_ws + 256 * i + w * 64 + lane),
            (lu32*)(s_pb + 256 * i + w * 64),
            16, 0, 0);
    s_psq[tid] = psq_ws[tid];
    s_psq[tid + 256] = psq_ws[tid + 256];
    s_y[tid] = y[row0 + tid];

    // convert to A fragments + row norms
    short8 afrag[4][2];
#pragma unroll
    for (int rt = 0; rt < 4; ++rt) {
        float part = 0.f;
#pragma unroll
        for (int kk = 0; kk < 2; ++kk) {
            float4 a0 = raw[rt * 4 + kk * 2 + 0];
            float4 a1 = raw[rt * 4 + kk * 2 + 1];
            part += a0.x * a0.x + a0.y * a0.y + a0.z * a0.z + a0.w * a0.w +
                    a1.x * a1.x + a1.y * a1.y + a1.z * a1.z + a1.w * a1.w;
            union { unsigned u[4]; short8 s; } pk;
            pk.u[0] = cvt_pk_bf16(a0.x, a0.y);
            pk.u[1] = cvt_pk_bf16(a0.z, a0.w);
            pk.u[2] = cvt_pk_bf16(a1.x, a1.y);
            pk.u[3] = cvt_pk_bf16(a1.z, a1.w);
            afrag[rt][kk] = pk.s;
        }
        part += __shfl_xor(part, 16);
        part += __shfl_xor(part, 32);
        if (g == 0) s_xsq[w][rt * 16 + col] = part;
    }

    __syncthreads();  // drains vmcnt (DMA staging) + lgkm; only barrier

    // corr <=> jcv[rt][r] == jj
    int jcv[4][4];
#pragma unroll
    for (int rt = 0; rt < 4; ++rt)
#pragma unroll
        for (int r = 0; r < 4; ++r) {
            int yv = s_y[w * 64 + rt * 16 + g * 4 + r];
            jcv[rt][r] = ((yv & 15) == col) ? (yv >> 4) : 15;
        }

    float m1[4][4], m2[4][4];
#pragma unroll
    for (int rt = 0; rt < 4; ++rt)
#pragma unroll
        for (int r = 0; r < 4; ++r) { m1[rt][r] = INFINITY; m2[rt][r] = INFINITY; }

    // per-lane constant LDS bases; t offsets fold into ds immediates
    const int sw = (col & 7) << 4;
    const char* s_pb_c = (const char*)s_pb;
    const char* pb0 = s_pb_c + col * 128 + ((g * 16) ^ sw);
    const char* pb1 = s_pb_c + col * 128 + ((g * 16 + 64) ^ sw);
    const char* pqc = (const char*)s_psq + col * 16;

#pragma unroll
    for (int jj = 0; jj < 8; ++jj) {
        // de-convoy: each wave walks the proto tiles in a rotated order
        const int jjr = (jj + 2 * w) & 7;
        const int bj = jjr * 8192;
        const f32x4 psqv = *reinterpret_cast<const f32x4*>(pqc + jjr * 256);
        float vmin[4][4];
#pragma unroll
        for (int rt = 0; rt < 4; ++rt)
#pragma unroll
            for (int r = 0; r < 4; ++r) vmin[rt][r] = INFINITY;
#pragma unroll
        for (int t = 0; t < 4; ++t) {
            short8 b0 = *reinterpret_cast<const short8*>(pb0 + bj + t * 2048);
            short8 b1 = *reinterpret_cast<const short8*>(pb1 + bj + t * 2048);
            const float sd = psqv[t];
#pragma unroll
            for (int rt = 0; rt < 4; ++rt) {
                f32x4 a = {sd, sd, sd, sd};  // seed acc with ||p||^2
                a = __builtin_amdgcn_mfma_f32_16x16x32_bf16(afrag[rt][0], b0, a, 0, 0, 0);
                a = __builtin_amdgcn_mfma_f32_16x16x32_bf16(afrag[rt][1], b1, a, 0, 0, 0);
#pragma unroll
                for (int r = 0; r < 4; ++r)
                    vmin[rt][r] = fminf(vmin[rt][r], a[r]);
            }
        }
#pragma unroll
        for (int rt = 0; rt < 4; ++rt)
#pragma unroll
            for (int r = 0; r < 4; ++r) {
                float v = vmin[rt][r];
                bool corr = (jcv[rt][r] == jjr);
                m1[rt][r] = corr ? v : m1[rt][r];                  // hits exactly once
                m2[rt][r] = corr ? m2[rt][r] : fminf(m2[rt][r], v);
            }
    }

    // epilogue: DPP min over 16 proto-columns (within 16-lane rows), mu/sigmoid
    float lsum = 0.f;
#pragma unroll
    for (int rt = 0; rt < 4; ++rt)
#pragma unroll
        for (int r = 0; r < 4; ++r) {
            float a1 = m1[rt][r], a2 = m2[rt][r];
            a1 = dpp_min<0xB1>(a1);  a2 = dpp_min<0xB1>(a2);   // xor 1
            a1 = dpp_min<0x4E>(a1);  a2 = dpp_min<0x4E>(a2);   // xor 2
            a1 = dpp_min<0x141>(a1); a2 = dpp_min<0x141>(a2);  // xor 4
            a1 = dpp_min<0x140>(a1); a2 = dpp_min<0x140>(a2);  // xor 8
            float xsq = s_xsq[w][rt * 16 + g * 4 + r];
            float d1 = xsq + a1, d2 = xsq + a2;
            float mu = (d1 - d2) / (d1 + d2 + 1e-9f);
            float sig = 1.f / (1.f + __expf(-mu));
            lsum += (col == 0) ? sig : 0.f;
        }
#pragma unroll
    for (int mk = 1; mk <= 32; mk <<= 1) lsum += __shfl_xor(lsum, mk);
    if (lane == 0) s_red[w] = lsum;
    __syncthreads();
    if (tid == 0)
        partial[blockIdx.x] = (s_red[0] + s_red[1]) + (s_red[2] + s_red[3]);
}

__global__ __launch_bounds__(256) void glvq_finalize(
    const float* __restrict__ partial, int nparts, float* __restrict__ out)
{
    __shared__ float s_red[256];
    const int tid = threadIdx.x;
    float acc = 0.f;
    for (int i = tid; i < nparts; i += 256) acc += partial[i];
    s_red[tid] = acc;
    __syncthreads();
#pragma unroll
    for (int s = 128; s >= 1; s >>= 1) {
        if (tid < s) s_red[tid] += s_red[tid + s];
        __syncthreads();
    }
    if (tid == 0) out[0] = s_red[0] * (1.0f / (float)NROWS);
}

extern "C" void kernel_launch(void* const* d_in, const int* in_sizes, int n_in,
                              void* d_out, int out_size, void* d_ws, size_t ws_size,
                              hipStream_t stream) {
    const float* x = (const float*)d_in[0];
    const float* protos = (const float*)d_in[1];
    const int* y = (const int*)d_in[2];
    float* out = (float*)d_out;

    // ws layout: [0..4K) partials | [4K..6K) psq | [6K..70K) bf16 protos
    float* partial = (float*)d_ws;
    float* psq_ws = partial + NBLK;
    uint4* pb_ws = (uint4*)((char*)d_ws + NBLK * 4 + NPROT * 4);

    glvq_prep<<<8, 64, 0, stream>>>(protos, psq_ws, pb_ws);
    glvq_main<<<NBLK, 256, 0, stream>>>(x, y, psq_ws, pb_ws, partial);
    glvq_finalize<<<1, 256, 0, stream>>>(partial, NBLK, out);
}